// Round 8
// baseline (586.476 us; speedup 1.0000x reference)
//
#include <hip/hip_runtime.h>
#include <hip/hip_bf16.h>

#define N_TOK 131072
#define DIM   512
#define HID   512
#define NEXP  10

using bf16x8 = __attribute__((ext_vector_type(8))) short;
using f32x4  = __attribute__((ext_vector_type(4))) float;

__device__ __forceinline__ short f2bf(float f) {
    union { float f; unsigned u; } v; v.f = f;
    unsigned u = v.u;
    return (short)((u + 0x7FFFu + ((u >> 16) & 1u)) >> 16);   // RNE
}

// ---------------- router: logits = x @ Wr^T + br, argmax; also emits xb = bf16(x) ----------------
__global__ __launch_bounds__(256) void router_kernel(
    const float* __restrict__ x, const float* __restrict__ Wr,
    const float* __restrict__ br, int* __restrict__ eid,
    float* __restrict__ ids_out, int* __restrict__ counts,
    short* __restrict__ xb)
{
    __shared__ float wr[NEXP][DIM];
    __shared__ int lcnt[NEXP];
    int tid = threadIdx.x;
    for (int i = tid; i < NEXP * DIM / 4; i += 256)
        ((float4*)wr)[i] = ((const float4*)Wr)[i];
    if (tid < NEXP) lcnt[tid] = 0;
    __syncthreads();

    int lane  = tid & 63;
    int wave  = tid >> 6;
    int gwave = blockIdx.x * 4 + wave;
    int nwav  = gridDim.x * 4;

    for (int t = gwave; t < N_TOK; t += nwav) {
        const float4* xr = (const float4*)(x + (size_t)t * DIM);
        float4 v0 = xr[lane * 2], v1 = xr[lane * 2 + 1];
        float xf[8] = {v0.x, v0.y, v0.z, v0.w, v1.x, v1.y, v1.z, v1.w};
        bf16x8 p;
        #pragma unroll
        for (int j = 0; j < 8; ++j) p[j] = f2bf(xf[j]);
        *(bf16x8*)(xb + (size_t)t * DIM + lane * 8) = p;

        float dot[NEXP];
        #pragma unroll
        for (int e = 0; e < NEXP; ++e) {
            const float* wv = &wr[e][lane * 8];
            float s = 0.f;
            #pragma unroll
            for (int j = 0; j < 8; ++j) s = fmaf(xf[j], wv[j], s);
            dot[e] = s;
        }
        #pragma unroll
        for (int off = 32; off > 0; off >>= 1) {
            #pragma unroll
            for (int e = 0; e < NEXP; ++e) dot[e] += __shfl_xor(dot[e], off, 64);
        }
        if (lane == 0) {
            int best = 0; float bv = dot[0] + br[0];
            #pragma unroll
            for (int e = 1; e < NEXP; ++e) {
                float v = dot[e] + br[e];
                if (v > bv) { bv = v; best = e; }
            }
            eid[t] = best;
            ids_out[t] = (float)best;
            atomicAdd(&lcnt[best], 1);
        }
    }
    __syncthreads();
    if (tid < NEXP) atomicAdd(&counts[tid], lcnt[tid]);
}

// ---------------- prefix sums: token offsets + tile offsets (64-row tiles) ----------------
__global__ void offsets_kernel(const int* __restrict__ counts,
                               int* __restrict__ offsets, int* __restrict__ toff)
{
    if (threadIdx.x == 0) {
        int acc = 0, ta = 0;
        for (int e = 0; e < NEXP; ++e) {
            offsets[e] = acc; toff[e] = ta;
            acc += counts[e]; ta += (counts[e] + 63) >> 6;
        }
        offsets[NEXP] = acc; toff[NEXP] = ta;
    }
}

// ---------------- bucket scatter: perm[offset[e] + pos] = token ----------------
__global__ __launch_bounds__(256) void scatter_kernel(
    const int* __restrict__ eid, const int* __restrict__ offsets,
    int* __restrict__ cursors, int* __restrict__ perm)
{
    __shared__ int lcnt[NEXP], lbase[NEXP];
    int tid = threadIdx.x;
    if (tid < NEXP) lcnt[tid] = 0;
    __syncthreads();
    int t = blockIdx.x * 256 + tid;
    int e = 0, lpos = 0;
    if (t < N_TOK) {
        e = eid[t];
        lpos = atomicAdd(&lcnt[e], 1);
    }
    __syncthreads();
    if (tid < NEXP) lbase[tid] = atomicAdd(&cursors[tid], lcnt[tid]);
    __syncthreads();
    if (t < N_TOK) perm[offsets[e] + lbase[e] + lpos] = t;
}

// ---- transpose-convert weights: [512 k][512 n] f32 -> k-blocked bf16 [16][512 n][32 k] ----
__global__ __launch_bounds__(256) void wconvert_kernel(
    const float* __restrict__ W1, const float* __restrict__ W2,
    short* __restrict__ W1b, short* __restrict__ W2b)
{
    int mat = blockIdx.z;
    const float* src = (mat < NEXP) ? W1 + (size_t)mat * 512 * 512
                                    : W2 + (size_t)(mat - NEXP) * 512 * 512;
    short* dst = (mat < NEXP) ? W1b + (size_t)mat * 512 * 512
                              : W2b + (size_t)(mat - NEXP) * 512 * 512;
    __shared__ float tile[64][65];
    int r0 = blockIdx.y * 64, c0 = blockIdx.x * 64;   // r0 = k base, c0 = n base
    int tid = threadIdx.x;
    int tr = tid >> 4, tc4 = (tid & 15) * 4;
    #pragma unroll
    for (int i = 0; i < 4; ++i) {
        float4 v = *(const float4*)(src + (size_t)(r0 + i * 16 + tr) * 512 + c0 + tc4);
        tile[i * 16 + tr][tc4 + 0] = v.x; tile[i * 16 + tr][tc4 + 1] = v.y;
        tile[i * 16 + tr][tc4 + 2] = v.z; tile[i * 16 + tr][tc4 + 3] = v.w;
    }
    __syncthreads();
    int s   = (r0 + tc4) >> 5;     // 32k-block
    int kin = (r0 + tc4) & 31;
    #pragma unroll
    for (int i = 0; i < 4; ++i) {
        int cc = i * 16 + tr;      // n within tile
        ushort4 o;
        o.x = (ushort)f2bf(tile[tc4 + 0][cc]); o.y = (ushort)f2bf(tile[tc4 + 1][cc]);
        o.z = (ushort)f2bf(tile[tc4 + 2][cc]); o.w = (ushort)f2bf(tile[tc4 + 3][cc]);
        *(ushort4*)(dst + (size_t)s * 16384 + (size_t)(c0 + cc) * 32 + kin) = o;
    }
}

// ---------------- direct-to-register MFMA expert GEMM: no LDS, no barriers ----------------
// Each wave independently computes a 64x64 output tile (4x4 of 16x16x32 MFMA frags).
// Per K-step (32): 4 A-frag + 4 B-frag global_load_dwordx4 straight to VGPRs, 16 MFMA.
// Block = 4 waves side-by-side over 256 cols (A loads identical across waves -> L1 hits).
// LAYER==1: A = gathered xb rows, out = relu(.+b1) -> h (bf16, packed by perm order)
// LAYER==2: A = packed h rows,    out = . + b2 -> out[tok] (f32, scattered)
template<int LAYER>
__global__ __launch_bounds__(256, 3) void expert_gemm(
    const short* __restrict__ xb, const short* __restrict__ hA,
    const short* __restrict__ WT, const float* __restrict__ bias,
    const int* __restrict__ offsets, const int* __restrict__ toff,
    const int* __restrict__ perm,
    short* __restrict__ hOut, float* __restrict__ out)
{
    int g = blockIdx.x;
    if (g >= toff[NEXP]) return;
    int e = 0;
    #pragma unroll
    for (int k = 1; k < NEXP; ++k) e += (g >= toff[k]);
    int beg = offsets[e], cnt = offsets[e + 1] - beg;
    int m0 = (g - toff[e]) * 64;
    int nb = blockIdx.y * 256;

    int tid = threadIdx.x, lane = tid & 63, wq = tid >> 6;
    int lrow = lane & 15, kq = lane >> 4;

    const short* WTe = WT + (size_t)e * 512 * 512;

    // per-lane A-frag row pointers (clamped); rows i*16+lrow, k-slice kq*8
    const short* aP[4];
    #pragma unroll
    for (int i = 0; i < 4; ++i) {
        int r = min(m0 + i * 16 + lrow, cnt - 1);
        if (LAYER == 1) aP[i] = xb + (size_t)perm[beg + r] * DIM + kq * 8;
        else            aP[i] = hA + (size_t)(beg + r) * HID + kq * 8;
    }
    // per-lane B-frag col pointers; cols wq*64+j*16+lrow, k-slice kq*8 (k-blocked layout)
    const short* bP[4];
    #pragma unroll
    for (int j = 0; j < 4; ++j) {
        int c = nb + wq * 64 + j * 16 + lrow;
        bP[j] = WTe + (size_t)c * 32 + kq * 8;
    }

    f32x4 acc[4][4];
    #pragma unroll
    for (int i = 0; i < 4; ++i)
        #pragma unroll
        for (int j = 0; j < 4; ++j) acc[i][j] = (f32x4){0.f, 0.f, 0.f, 0.f};

    // main loop: 16 K-steps of 32; loads -> regs, 16 MFMA; no LDS, no barriers
    #pragma unroll 4
    for (int t = 0; t < 16; ++t) {
        bf16x8 af[4], bv[4];
        #pragma unroll
        for (int i = 0; i < 4; ++i) af[i] = *(const bf16x8*)(aP[i] + t * 32);
        #pragma unroll
        for (int j = 0; j < 4; ++j) bv[j] = *(const bf16x8*)(bP[j] + (size_t)t * 16384);
        #pragma unroll
        for (int i = 0; i < 4; ++i)
            #pragma unroll
            for (int j = 0; j < 4; ++j)
                acc[i][j] = __builtin_amdgcn_mfma_f32_16x16x32_bf16(af[i], bv[j], acc[i][j], 0, 0, 0);
    }

    // ---- epilogue ----
    const float* be = bias + (size_t)e * 512;
    int colb = nb + wq * 64 + lrow;
    float bvv[4];
    #pragma unroll
    for (int j = 0; j < 4; ++j) bvv[j] = be[colb + j * 16];

    #pragma unroll
    for (int i = 0; i < 4; ++i) {
        #pragma unroll
        for (int q = 0; q < 4; ++q) {
            int rr = i * 16 + kq * 4 + q;
            if (m0 + rr < cnt) {
                if (LAYER == 1) {
                    short* hp = hOut + (size_t)(beg + m0 + rr) * HID + colb;
                    #pragma unroll
                    for (int j = 0; j < 4; ++j) {
                        float v = acc[i][j][q] + bvv[j];
                        hp[j * 16] = f2bf(v > 0.f ? v : 0.f);
                    }
                } else {
                    float* op = out + (size_t)perm[beg + m0 + rr] * HID + colb;
                    #pragma unroll
                    for (int j = 0; j < 4; ++j)
                        op[j * 16] = acc[i][j][q] + bvv[j];
                }
            }
        }
    }
}

extern "C" void kernel_launch(void* const* d_in, const int* in_sizes, int n_in,
                              void* d_out, int out_size, void* d_ws, size_t ws_size,
                              hipStream_t stream)
{
    const float* x  = (const float*)d_in[0];
    const float* Wr = (const float*)d_in[1];
    const float* br = (const float*)d_in[2];
    const float* W1 = (const float*)d_in[3];
    const float* b1 = (const float*)d_in[4];
    const float* W2 = (const float*)d_in[5];
    const float* b2 = (const float*)d_in[6];

    float* out     = (float*)d_out;
    float* ids_out = out + (size_t)N_TOK * HID;

    char* ws     = (char*)d_ws;
    int* counts  = (int*)ws;            // 16 ints
    int* offsets = counts + 16;         // 11 used
    int* toff    = counts + 32;         // 11 used
    int* cursors = counts + 48;         // 16
    int* eid     = (int*)(ws + 1024);
    int* perm    = eid + N_TOK;
    short* W1b   = (short*)(ws + 1024 + (size_t)2 * N_TOK * 4);
    short* W2b   = W1b + (size_t)NEXP * 512 * 512;
    short* h     = W2b + (size_t)NEXP * 512 * 512;
    short* xb    = h   + (size_t)N_TOK * HID;

    hipMemsetAsync(d_ws, 0, 1024, stream);
    router_kernel<<<2048, 256, 0, stream>>>(x, Wr, br, eid, ids_out, counts, xb);
    wconvert_kernel<<<dim3(8, 8, 2 * NEXP), 256, 0, stream>>>(W1, W2, W1b, W2b);
    offsets_kernel<<<1, 64, 0, stream>>>(counts, offsets, toff);
    scatter_kernel<<<512, 256, 0, stream>>>(eid, offsets, cursors, perm);

    int ntiles = (N_TOK + 63) / 64 + NEXP;   // upper bound on 64-row tiles
    expert_gemm<1><<<dim3(ntiles, 2), 256, 0, stream>>>(xb, nullptr, W1b, b1, offsets, toff, perm, h, nullptr);
    expert_gemm<2><<<dim3(ntiles, 2), 256, 0, stream>>>(nullptr, h, W2b, b2, offsets, toff, perm, nullptr, out);
}

// Round 9
// 497.604 us; speedup vs baseline: 1.1786x; 1.1786x over previous
//
#include <hip/hip_runtime.h>
#include <hip/hip_bf16.h>

#define N_TOK 131072
#define DIM   512
#define HID   512
#define NEXP  10

using bf16x8 = __attribute__((ext_vector_type(8))) short;
using f32x4  = __attribute__((ext_vector_type(4))) float;

__device__ __forceinline__ short f2bf(float f) {
    union { float f; unsigned u; } v; v.f = f;
    unsigned u = v.u;
    return (short)((u + 0x7FFFu + ((u >> 16) & 1u)) >> 16);   // RNE
}

#define GLOAD16(g, l) __builtin_amdgcn_global_load_lds( \
    (const __attribute__((address_space(1))) void*)(g),  \
    (__attribute__((address_space(3))) void*)(l), 16, 0, 0)

// ---------------- router: logits = x @ Wr^T + br, argmax; also emits xb = bf16(x) ----------------
__global__ __launch_bounds__(256) void router_kernel(
    const float* __restrict__ x, const float* __restrict__ Wr,
    const float* __restrict__ br, int* __restrict__ eid,
    float* __restrict__ ids_out, int* __restrict__ counts,
    short* __restrict__ xb)
{
    __shared__ float wr[NEXP][DIM];
    __shared__ int lcnt[NEXP];
    int tid = threadIdx.x;
    for (int i = tid; i < NEXP * DIM / 4; i += 256)
        ((float4*)wr)[i] = ((const float4*)Wr)[i];
    if (tid < NEXP) lcnt[tid] = 0;
    __syncthreads();

    int lane  = tid & 63;
    int wave  = tid >> 6;
    int gwave = blockIdx.x * 4 + wave;
    int nwav  = gridDim.x * 4;

    for (int t = gwave; t < N_TOK; t += nwav) {
        const float4* xr = (const float4*)(x + (size_t)t * DIM);
        float4 v0 = xr[lane * 2], v1 = xr[lane * 2 + 1];
        float xf[8] = {v0.x, v0.y, v0.z, v0.w, v1.x, v1.y, v1.z, v1.w};
        bf16x8 p;
        #pragma unroll
        for (int j = 0; j < 8; ++j) p[j] = f2bf(xf[j]);
        *(bf16x8*)(xb + (size_t)t * DIM + lane * 8) = p;

        float dot[NEXP];
        #pragma unroll
        for (int e = 0; e < NEXP; ++e) {
            const float* wv = &wr[e][lane * 8];
            float s = 0.f;
            #pragma unroll
            for (int j = 0; j < 8; ++j) s = fmaf(xf[j], wv[j], s);
            dot[e] = s;
        }
        #pragma unroll
        for (int off = 32; off > 0; off >>= 1) {
            #pragma unroll
            for (int e = 0; e < NEXP; ++e) dot[e] += __shfl_xor(dot[e], off, 64);
        }
        if (lane == 0) {
            int best = 0; float bv = dot[0] + br[0];
            #pragma unroll
            for (int e = 1; e < NEXP; ++e) {
                float v = dot[e] + br[e];
                if (v > bv) { bv = v; best = e; }
            }
            eid[t] = best;
            ids_out[t] = (float)best;
            atomicAdd(&lcnt[best], 1);
        }
    }
    __syncthreads();
    if (tid < NEXP) atomicAdd(&counts[tid], lcnt[tid]);
}

// ---------------- prefix sums: token offsets + tile offsets (128-row tiles) ----------------
__global__ void offsets_kernel(const int* __restrict__ counts,
                               int* __restrict__ offsets, int* __restrict__ toff)
{
    if (threadIdx.x == 0) {
        int acc = 0, ta = 0;
        for (int e = 0; e < NEXP; ++e) {
            offsets[e] = acc; toff[e] = ta;
            acc += counts[e]; ta += (counts[e] + 127) >> 7;
        }
        offsets[NEXP] = acc; toff[NEXP] = ta;
    }
}

// ---------------- bucket scatter: perm[offset[e] + pos] = token ----------------
__global__ __launch_bounds__(256) void scatter_kernel(
    const int* __restrict__ eid, const int* __restrict__ offsets,
    int* __restrict__ cursors, int* __restrict__ perm)
{
    __shared__ int lcnt[NEXP], lbase[NEXP];
    int tid = threadIdx.x;
    if (tid < NEXP) lcnt[tid] = 0;
    __syncthreads();
    int t = blockIdx.x * 256 + tid;
    int e = 0, lpos = 0;
    if (t < N_TOK) {
        e = eid[t];
        lpos = atomicAdd(&lcnt[e], 1);
    }
    __syncthreads();
    if (tid < NEXP) lbase[tid] = atomicAdd(&cursors[tid], lcnt[tid]);
    __syncthreads();
    if (t < N_TOK) perm[offsets[e] + lbase[e] + lpos] = t;
}

// ---- transpose-convert weights: [512 k][512 n] f32 -> k-blocked bf16 [16][512 n][32 k] ----
__global__ __launch_bounds__(256) void wconvert_kernel(
    const float* __restrict__ W1, const float* __restrict__ W2,
    short* __restrict__ W1b, short* __restrict__ W2b)
{
    int mat = blockIdx.z;
    const float* src = (mat < NEXP) ? W1 + (size_t)mat * 512 * 512
                                    : W2 + (size_t)(mat - NEXP) * 512 * 512;
    short* dst = (mat < NEXP) ? W1b + (size_t)mat * 512 * 512
                              : W2b + (size_t)(mat - NEXP) * 512 * 512;
    __shared__ float tile[64][65];
    int r0 = blockIdx.y * 64, c0 = blockIdx.x * 64;   // r0 = k base, c0 = n base
    int tid = threadIdx.x;
    int tr = tid >> 4, tc4 = (tid & 15) * 4;
    #pragma unroll
    for (int i = 0; i < 4; ++i) {
        float4 v = *(const float4*)(src + (size_t)(r0 + i * 16 + tr) * 512 + c0 + tc4);
        tile[i * 16 + tr][tc4 + 0] = v.x; tile[i * 16 + tr][tc4 + 1] = v.y;
        tile[i * 16 + tr][tc4 + 2] = v.z; tile[i * 16 + tr][tc4 + 3] = v.w;
    }
    __syncthreads();
    int s   = (r0 + tc4) >> 5;     // 32k-block
    int kin = (r0 + tc4) & 31;
    #pragma unroll
    for (int i = 0; i < 4; ++i) {
        int cc = i * 16 + tr;      // n within tile
        ushort4 o;
        o.x = (ushort)f2bf(tile[tc4 + 0][cc]); o.y = (ushort)f2bf(tile[tc4 + 1][cc]);
        o.z = (ushort)f2bf(tile[tc4 + 2][cc]); o.w = (ushort)f2bf(tile[tc4 + 3][cc]);
        *(ushort4*)(dst + (size_t)s * 16384 + (size_t)(c0 + cc) * 32 + kin) = o;
    }
}

// ---------------- MFMA expert GEMM: 128 rows x 512 cols (2 halves of 256), K=512, 8 waves ----------------
// R5-proven 3-buffer / counted-vmcnt(3) / raw-s_barrier ledger, run twice (half-loop) so the
// second half's A reads hit this block's own XCD L2 (kills the cross-XCD 2x fetch).
// LDS 16B-slot swizzle q^((row>>1)&3) (R7-verified: conflicts -> 0), source-side + read-side.
// LAYER==1: A = gathered xb rows; epilogue bounces acc through LDS -> coalesced bf16x8 h stores.
// LAYER==2: A = packed h rows; direct f32 scatter stores (no amplification measured).
template<int LAYER>
__global__ __launch_bounds__(512, 4) void expert_gemm(
    const short* __restrict__ xb, const short* __restrict__ hA,
    const short* __restrict__ WT, const float* __restrict__ bias,
    const int* __restrict__ offsets, const int* __restrict__ toff,
    const int* __restrict__ perm,
    short* __restrict__ hOut, float* __restrict__ out)
{
    int g = blockIdx.x;
    if (g >= toff[NEXP]) return;
    int e = 0;
    #pragma unroll
    for (int k = 1; k < NEXP; ++k) e += (g >= toff[k]);
    int beg = offsets[e], cnt = offsets[e + 1] - beg;
    int m0 = (g - toff[e]) * 128;

    __shared__ int toks[128];
    __shared__ char SMEM[73728];   // A bufs 3x8KB @ [0,24K); B bufs 3x16KB @ [24K,72K); bounce reuses [0,67.6K)

    int tid = threadIdx.x, lane = tid & 63, w = tid >> 6;
    if (tid < 128) toks[tid] = perm[beg + min(m0 + tid, cnt - 1)];
    __syncthreads();

    // ---- staging addresses (source pre-swizzled; LDS dest linear = tid*16) ----
    const short* WTe = WT + (size_t)e * 512 * 512;
    int srow = w * 16 + (lane >> 2);       // 0..127
    int kqp  = lane & 3;                   // physical 16B slot
    int ql   = kqp ^ ((srow >> 1) & 3);    // logical k-quarter stored at this slot
    const short* aS;
    if (LAYER == 1) aS = xb + (size_t)toks[srow] * DIM + ql * 8;
    else            aS = hA + (size_t)(beg + min(m0 + srow, cnt - 1)) * HID + ql * 8;
    const short* bS = WTe + (size_t)srow * 32 + ql * 8;    // + nb*32 + t*16384; +4096 for rows+128

    auto stage = [&](int t, int b, int nb) {
        const short* bs = bS + nb * 32 + t * 16384;
        GLOAD16(bs,            SMEM + 24576 + b * 16384 + tid * 16);
        GLOAD16(bs + 4096,     SMEM + 24576 + b * 16384 + 8192 + tid * 16);
        GLOAD16(aS + t * 32,   SMEM + b * 8192 + tid * 16);
    };

    // ---- fragment read offsets (swizzled, bytes within buffer) ----
    int wr = w >> 2, wc = w & 3, lrow = lane & 15, kq = lane >> 4;
    int offA[4], offB[4];
    #pragma unroll
    for (int i = 0; i < 4; ++i) {
        int r = wr * 64 + i * 16 + lrow;
        offA[i] = r * 64 + (kq ^ ((r >> 1) & 3)) * 16;
    }
    #pragma unroll
    for (int j = 0; j < 4; ++j) {
        int r = wc * 64 + j * 16 + lrow;
        offB[j] = r * 64 + (kq ^ ((r >> 1) & 3)) * 16;
    }

    const float* be = bias + (size_t)e * 512;

    #pragma unroll 1
    for (int half = 0; half < 2; ++half) {
        int nb = half * 256;

        f32x4 acc[4][4];
        #pragma unroll
        for (int i = 0; i < 4; ++i)
            #pragma unroll
            for (int j = 0; j < 4; ++j) acc[i][j] = (f32x4){0.f, 0.f, 0.f, 0.f};

        auto comp = [&](int b) {
            bf16x8 af[4], bv[4];
            #pragma unroll
            for (int i = 0; i < 4; ++i)
                af[i] = *(const bf16x8*)(SMEM + b * 8192 + offA[i]);
            #pragma unroll
            for (int j = 0; j < 4; ++j)
                bv[j] = *(const bf16x8*)(SMEM + 24576 + b * 16384 + offB[j]);
            __builtin_amdgcn_s_setprio(1);
            #pragma unroll
            for (int i = 0; i < 4; ++i)
                #pragma unroll
                for (int j = 0; j < 4; ++j)
                    acc[i][j] = __builtin_amdgcn_mfma_f32_16x16x32_bf16(af[i], bv[j], acc[i][j], 0, 0, 0);
            __builtin_amdgcn_s_setprio(0);
        };

        // prologue (R5 ledger): 6 loads out, wait to 3 -> stage(0) resident
        stage(0, 0, nb);
        stage(1, 1, nb);
        asm volatile("s_waitcnt vmcnt(3)" ::: "memory");
        __builtin_amdgcn_s_barrier();

        #pragma unroll
        for (int t = 0; t < 16; ++t) {
            if (t + 2 < 16) stage(t + 2, (t + 2) % 3, nb);
            comp(t % 3);
            if (t == 15) break;
            if (t + 2 < 16) asm volatile("s_waitcnt vmcnt(3)" ::: "memory");
            else            asm volatile("s_waitcnt vmcnt(0)" ::: "memory");
            __builtin_amdgcn_s_barrier();
        }
        __builtin_amdgcn_s_barrier();   // all comps done before LDS reuse / next-half restage

        // ---- epilogue ----
        int colb = nb + wc * 64 + lrow;
        float bvv[4];
        #pragma unroll
        for (int j = 0; j < 4; ++j) bvv[j] = be[colb + j * 16];

        if (LAYER == 1) {
            // bounce acc -> LDS (row stride 528B = 264 shorts, +4 bank shift/row)
            #pragma unroll
            for (int i = 0; i < 4; ++i)
                #pragma unroll
                for (int q = 0; q < 4; ++q) {
                    int rr = wr * 64 + i * 16 + kq * 4 + q;
                    #pragma unroll
                    for (int j = 0; j < 4; ++j) {
                        int c = wc * 64 + j * 16 + lrow;
                        float v = acc[i][j][q] + bvv[j];
                        *(short*)(SMEM + rr * 528 + c * 2) = f2bf(v > 0.f ? v : 0.f);
                    }
                }
            __syncthreads();
            // coalesced readback: 32 chunks x 16B per row, 16 row-groups of 8
            int ch = tid & 31, rg = tid >> 5;
            #pragma unroll
            for (int s = 0; s < 8; ++s) {
                int row = rg * 8 + s;
                if (m0 + row < cnt) {
                    bf16x8 vv = *(const bf16x8*)(SMEM + row * 528 + ch * 16);
                    *(bf16x8*)(hOut + (size_t)(beg + m0 + row) * HID + nb + ch * 8) = vv;
                }
            }
            __syncthreads();   // before next half restages SMEM
        } else {
            #pragma unroll
            for (int i = 0; i < 4; ++i)
                #pragma unroll
                for (int q = 0; q < 4; ++q) {
                    int rr = wr * 64 + i * 16 + kq * 4 + q;
                    if (m0 + rr < cnt) {
                        float* op = out + (size_t)toks[rr] * HID + colb;
                        #pragma unroll
                        for (int j = 0; j < 4; ++j)
                            op[j * 16] = acc[i][j][q] + bvv[j];
                    }
                }
        }
    }
}

extern "C" void kernel_launch(void* const* d_in, const int* in_sizes, int n_in,
                              void* d_out, int out_size, void* d_ws, size_t ws_size,
                              hipStream_t stream)
{
    const float* x  = (const float*)d_in[0];
    const float* Wr = (const float*)d_in[1];
    const float* br = (const float*)d_in[2];
    const float* W1 = (const float*)d_in[3];
    const float* b1 = (const float*)d_in[4];
    const float* W2 = (const float*)d_in[5];
    const float* b2 = (const float*)d_in[6];

    float* out     = (float*)d_out;
    float* ids_out = out + (size_t)N_TOK * HID;

    char* ws     = (char*)d_ws;
    int* counts  = (int*)ws;            // 16 ints
    int* offsets = counts + 16;         // 11 used
    int* toff    = counts + 32;         // 11 used
    int* cursors = counts + 48;         // 16
    int* eid     = (int*)(ws + 1024);
    int* perm    = eid + N_TOK;
    short* W1b   = (short*)(ws + 1024 + (size_t)2 * N_TOK * 4);
    short* W2b   = W1b + (size_t)NEXP * 512 * 512;
    short* h     = W2b + (size_t)NEXP * 512 * 512;
    short* xb    = h   + (size_t)N_TOK * HID;

    hipMemsetAsync(d_ws, 0, 1024, stream);
    router_kernel<<<2048, 256, 0, stream>>>(x, Wr, br, eid, ids_out, counts, xb);
    wconvert_kernel<<<dim3(8, 8, 2 * NEXP), 256, 0, stream>>>(W1, W2, W1b, W2b);
    offsets_kernel<<<1, 64, 0, stream>>>(counts, offsets, toff);
    scatter_kernel<<<512, 256, 0, stream>>>(eid, offsets, cursors, perm);

    int ntiles = (N_TOK + 127) / 128 + NEXP;   // upper bound on 128-row tiles
    expert_gemm<1><<<ntiles, 512, 0, stream>>>(xb, nullptr, W1b, b1, offsets, toff, perm, h, nullptr);
    expert_gemm<2><<<ntiles, 512, 0, stream>>>(nullptr, h, W2b, b2, offsets, toff, perm, nullptr, out);
}